// Round 5
// baseline (8625.835 us; speedup 1.0000x reference)
//
#include <hip/hip_runtime.h>
#include <cstdint>
#include <cstddef>

#define SEQ   2048
#define BATCH 64
#define HID   512

// ---------------------------------------------------------------------------
// proj GEMM: C[m][n] = sum_k A[m][k] * W[n][k] + bias[n]
// A: [M][512] row-major, W: [512][512] row-major (NT layout -> both row reads)
// BM=128 BN=128 BK=16, 256 threads, per-thread 8 rows x (4+4) cols
// ---------------------------------------------------------------------------
__global__ __launch_bounds__(256)
void proj_gemm(const float* __restrict__ A, const float* __restrict__ W,
               const float* __restrict__ bias, float* __restrict__ C)
{
    __shared__ float As[16][132];   // transposed: As[k][row], pad 132
    __shared__ float Bs[16][132];   // Bs[k][col]
    const int t  = threadIdx.x;
    const int bm = blockIdx.x >> 2;     // 1024 m-tiles
    const int bn = blockIdx.x & 3;      // 4 n-tiles
    const int m0 = bm * 128;
    const int n0 = bn * 128;
    const int tn = t & 15;
    const int tm = t >> 4;

    float acc[8][8];
#pragma unroll
    for (int i = 0; i < 8; ++i)
#pragma unroll
        for (int j = 0; j < 8; ++j) acc[i][j] = 0.f;

    const int lrow = t >> 2;   // 0..63
    const int lk4  = t & 3;    // float4 index within 16-wide k tile

    for (int kk = 0; kk < 512; kk += 16) {
#pragma unroll
        for (int i = 0; i < 2; ++i) {
            const int row = lrow + i * 64;
            float4 va = *(const float4*)&A[(size_t)(m0 + row) * 512 + kk + lk4 * 4];
            As[lk4 * 4 + 0][row] = va.x;
            As[lk4 * 4 + 1][row] = va.y;
            As[lk4 * 4 + 2][row] = va.z;
            As[lk4 * 4 + 3][row] = va.w;
            float4 vb = *(const float4*)&W[(size_t)(n0 + row) * 512 + kk + lk4 * 4];
            Bs[lk4 * 4 + 0][row] = vb.x;
            Bs[lk4 * 4 + 1][row] = vb.y;
            Bs[lk4 * 4 + 2][row] = vb.z;
            Bs[lk4 * 4 + 3][row] = vb.w;
        }
        __syncthreads();
#pragma unroll
        for (int k = 0; k < 16; ++k) {
            float4 a0 = *(const float4*)&As[k][tm * 8];
            float4 a1 = *(const float4*)&As[k][tm * 8 + 4];
            float4 b0 = *(const float4*)&Bs[k][tn * 4];
            float4 b1 = *(const float4*)&Bs[k][64 + tn * 4];
            float ar[8] = {a0.x, a0.y, a0.z, a0.w, a1.x, a1.y, a1.z, a1.w};
            float bc[8] = {b0.x, b0.y, b0.z, b0.w, b1.x, b1.y, b1.z, b1.w};
#pragma unroll
            for (int i = 0; i < 8; ++i)
#pragma unroll
                for (int j = 0; j < 8; ++j)
                    acc[i][j] = fmaf(ar[i], bc[j], acc[i][j]);
        }
        __syncthreads();
    }

    float4 bv0 = *(const float4*)&bias[n0 + tn * 4];
    float4 bv1 = *(const float4*)&bias[n0 + 64 + tn * 4];
    const float bb[8] = {bv0.x, bv0.y, bv0.z, bv0.w, bv1.x, bv1.y, bv1.z, bv1.w};
#pragma unroll
    for (int i = 0; i < 8; ++i) {
        const size_t rowoff = (size_t)(m0 + tm * 8 + i) * 512 + n0;
        float4 o0, o1;
        o0.x = acc[i][0] + bb[0]; o0.y = acc[i][1] + bb[1];
        o0.z = acc[i][2] + bb[2]; o0.w = acc[i][3] + bb[3];
        o1.x = acc[i][4] + bb[4]; o1.y = acc[i][5] + bb[5];
        o1.z = acc[i][6] + bb[6]; o1.w = acc[i][7] + bb[7];
        *(float4*)&C[rowoff + tn * 4] = o0;
        *(float4*)&C[rowoff + 64 + tn * 4] = o1;
    }
}

// fast tanh: 1 - 2/(exp2(2*log2e*x)+1); exact at +/-inf, ~1e-6 abs error
__device__ __forceinline__ float fast_tanh(float x)
{
    const float e = __builtin_amdgcn_exp2f(x * 2.88539008177793f);
    return fmaf(-2.0f, __builtin_amdgcn_rcpf(e + 1.0f), 1.0f);
}

// ---------------------------------------------------------------------------
// Recurrent scan. Persistent cooperative kernel, grid = 256 WGs x 512 thr.
// Group = batch element b (64 groups); 4 slice-WGs per group; slice s owns
// output rows [128s, 128s+128). W_hh slice held in VGPRs as 32 NAMED float4
// variables per thread (no array -> no scratch demotion; keepalive each step):
//   wave w (0..7), lane l: row = 128s + 16w + (l&15), k-span [(l>>4)*128,+128)
// Per step: poll tagged u64 h (own 128 rows self-routed via LDS at publish),
// ONE barrier, 128 reg-FMAs + broadcast ds_read_b128 of h, in-wave shfl_xor
// reduce (4 lanes/row), fast-tanh, publish tagged u64 (relaxed agent atomics,
// no fences/cache ops). proj load software-pipelined one step ahead.
// Parity double-buffer closes the overwrite race (proof as rounds 2-4).
// ---------------------------------------------------------------------------
#define W_LOAD(i) float4 w##i = *(const float4*)&wsrc[(i) * 4]
#define W_KEEP(i) asm volatile("" : "+v"(w##i.x), "+v"(w##i.y), "+v"(w##i.z), "+v"(w##i.w))
#define FMA_BLK(i, acc) do { float4 hh = hq[i]; \
    acc = fmaf(w##i.x, hh.x, acc); acc = fmaf(w##i.y, hh.y, acc); \
    acc = fmaf(w##i.z, hh.z, acc); acc = fmaf(w##i.w, hh.w, acc); } while (0)

__global__ __launch_bounds__(512, 2)
void rnn_scan(const float* __restrict__ proj, const float* __restrict__ Whh,
              const float* __restrict__ bhh, float* __restrict__ out,
              float* __restrict__ hidden, unsigned long long* __restrict__ hbuf)
{
    __shared__ float hS[2][528];   // [parity][512 + 4-float pad per 128]

    const int t   = threadIdx.x;
    const int bid = blockIdx.x;
    const int s   = bid >> 6;          // slice 0..3 (bid stride 64 -> same XCD)
    const int b   = bid & 63;          // batch element
    const int w   = t >> 6;            // wave 0..7
    const int l   = t & 63;
    const int lr  = l & 15;            // row-in-wave
    const int lc  = l >> 4;            // k-chunk 0..3
    const int row = s * 128 + w * 16 + lr;   // global output row

    // ---- one-time: W row-slice into 32 named float4 regs ----
    const float* wsrc = &Whh[(size_t)row * HID + lc * 128];
    W_LOAD(0);  W_LOAD(1);  W_LOAD(2);  W_LOAD(3);
    W_LOAD(4);  W_LOAD(5);  W_LOAD(6);  W_LOAD(7);
    W_LOAD(8);  W_LOAD(9);  W_LOAD(10); W_LOAD(11);
    W_LOAD(12); W_LOAD(13); W_LOAD(14); W_LOAD(15);
    W_LOAD(16); W_LOAD(17); W_LOAD(18); W_LOAD(19);
    W_LOAD(20); W_LOAD(21); W_LOAD(22); W_LOAD(23);
    W_LOAD(24); W_LOAD(25); W_LOAD(26); W_LOAD(27);
    W_LOAD(28); W_LOAD(29); W_LOAD(30); W_LOAD(31);

    const float breg = bhh[row];

    // init both LDS parities to h=0 (also covers step-0 self-routed slots)
    for (int i = t; i < 528; i += 512) { hS[0][i] = 0.f; hS[1][i] = 0.f; }
    __syncthreads();

    const bool own   = (t >> 7) == s;          // own k-range (self-routed)
    const int  pad_t = t + ((t >> 7) << 2);    // padded LDS index for k = t

    // proj pipeline: value for step 0
    const bool pub = (lc == 0);
    float pv_next = 0.f;
    if (pub) pv_next = proj[(size_t)b * HID + row];

    for (int step = 0; step < SEQ; ++step) {
        const int p = step & 1;

        // ---- consume pipelined proj; issue load for step+1 ----
        const float pv = pv_next;
        if (pub && step + 1 < SEQ)
            pv_next = proj[((size_t)(step + 1) * BATCH + b) * HID + row];

        // keepalive: all 32 W float4s must be in VGPRs here, every iteration
        W_KEEP(0);  W_KEEP(1);  W_KEEP(2);  W_KEEP(3);
        W_KEEP(4);  W_KEEP(5);  W_KEEP(6);  W_KEEP(7);
        W_KEEP(8);  W_KEEP(9);  W_KEEP(10); W_KEEP(11);
        W_KEEP(12); W_KEEP(13); W_KEEP(14); W_KEEP(15);
        W_KEEP(16); W_KEEP(17); W_KEEP(18); W_KEEP(19);
        W_KEEP(20); W_KEEP(21); W_KEEP(22); W_KEEP(23);
        W_KEEP(24); W_KEEP(25); W_KEEP(26); W_KEEP(27);
        W_KEEP(28); W_KEEP(29); W_KEEP(30); W_KEEP(31);

        // ---- poll + stage non-own h (one tagged u64 per thread; whole
        //      waves are own/non-own, so no divergence) ----
        if (!own) {
            const unsigned long long* src =
                hbuf + (size_t)p * (BATCH * HID) + (size_t)b * HID + t;
            const unsigned int want = (unsigned int)step;
            unsigned long long x;
            int spins = 0;
            for (;;) {
                x = __hip_atomic_load(src, __ATOMIC_RELAXED, __HIP_MEMORY_SCOPE_AGENT);
                if ((unsigned int)(x >> 32) == want) break;
                if (++spins > 1024) {              // hang-proofing only
                    __builtin_amdgcn_fence(__ATOMIC_ACQUIRE, "agent");
                    spins = 0;
                }
            }
            hS[p][pad_t] = __uint_as_float((unsigned int)x);
        }
        __syncthreads();   // the ONLY barrier per step

        // ---- matvec: named W regs x broadcast LDS h ----
        const float4* hq = (const float4*)&hS[p][lc * 132];
        float a0 = 0.f, a1 = 0.f, a2 = 0.f, a3 = 0.f;
        FMA_BLK(0,  a0); FMA_BLK(1,  a1); FMA_BLK(2,  a2); FMA_BLK(3,  a3);
        FMA_BLK(4,  a0); FMA_BLK(5,  a1); FMA_BLK(6,  a2); FMA_BLK(7,  a3);
        FMA_BLK(8,  a0); FMA_BLK(9,  a1); FMA_BLK(10, a2); FMA_BLK(11, a3);
        FMA_BLK(12, a0); FMA_BLK(13, a1); FMA_BLK(14, a2); FMA_BLK(15, a3);
        FMA_BLK(16, a0); FMA_BLK(17, a1); FMA_BLK(18, a2); FMA_BLK(19, a3);
        FMA_BLK(20, a0); FMA_BLK(21, a1); FMA_BLK(22, a2); FMA_BLK(23, a3);
        FMA_BLK(24, a0); FMA_BLK(25, a1); FMA_BLK(26, a2); FMA_BLK(27, a3);
        FMA_BLK(28, a0); FMA_BLK(29, a1); FMA_BLK(30, a2); FMA_BLK(31, a3);
        float sum = (a0 + a1) + (a2 + a3);
        // reduce across the 4 lanes sharing a row (l, l+16, l+32, l+48)
        sum += __shfl_xor(sum, 16, 64);
        sum += __shfl_xor(sum, 32, 64);

        // ---- tanh + publish (lanes lc==0), self-route own rows via LDS ----
        if (pub) {
            const float hn = fast_tanh(pv + breg + sum);
            out[((size_t)step * BATCH + b) * HID + row] = hn;
            const unsigned long long pk =
                ((unsigned long long)(unsigned int)(step + 1) << 32) |
                (unsigned long long)__float_as_uint(hn);
            __hip_atomic_store(
                &hbuf[(size_t)(p ^ 1) * (BATCH * HID) + (size_t)b * HID + row],
                pk, __ATOMIC_RELAXED, __HIP_MEMORY_SCOPE_AGENT);
            hS[p ^ 1][row + ((row >> 7) << 2)] = hn;   // self-route (own rows)
            if (step == SEQ - 1) hidden[(size_t)b * HID + row] = hn;
        }
        // no trailing barrier: next step's pre-barrier LDS writes touch only
        // parity p^1 slots disjoint from this step's hS[p] reads, and each
        // thread's own reads precede its next-step writes in program order.
    }
}

// ---------------------------------------------------------------------------
extern "C" void kernel_launch(void* const* d_in, const int* in_sizes, int n_in,
                              void* d_out, int out_size, void* d_ws, size_t ws_size,
                              hipStream_t stream)
{
    (void)in_sizes; (void)n_in; (void)out_size; (void)ws_size;

    const float* x    = (const float*)d_in[0];
    const float* Wih0 = (const float*)d_in[1];
    const float* Whh0 = (const float*)d_in[2];
    const float* bih0 = (const float*)d_in[3];
    const float* bhh0 = (const float*)d_in[4];
    const float* Wih1 = (const float*)d_in[5];
    const float* Whh1 = (const float*)d_in[6];
    const float* bih1 = (const float*)d_in[7];
    const float* bhh1 = (const float*)d_in[8];

    float* out1   = (float*)d_out;                        // [S][B][H]
    float* hidden = out1 + (size_t)SEQ * BATCH * HID;     // [2][B][H]

    float* proj = (float*)d_ws;                           // [S][B][H] f32
    unsigned long long* hbufA =
        (unsigned long long*)(proj + (size_t)SEQ * BATCH * HID);  // [2][B][H] u64
    unsigned long long* hbufB = hbufA + (size_t)2 * BATCH * HID;  // [2][B][H] u64

    // zero both layers' tagged h-state buffers (tag 0 == epoch 0, h = 0)
    hipMemsetAsync(hbufA, 0, (size_t)4 * BATCH * HID * sizeof(unsigned long long),
                   stream);

    // ---- layer 0 ----
    proj_gemm<<<dim3(4096), dim3(256), 0, stream>>>(x, Wih0, bih0, proj);
    {
        const float* p = proj; const float* w = Whh0; const float* bb = bhh0;
        float* o = out1; float* hd = hidden; unsigned long long* hb = hbufA;
        void* args[] = {&p, &w, &bb, &o, &hd, &hb};
        hipLaunchCooperativeKernel((const void*)rnn_scan, dim3(256), dim3(512),
                                   args, 0, stream);
    }

    // ---- layer 1 (out0 staged in d_out's out1 region) ----
    proj_gemm<<<dim3(4096), dim3(256), 0, stream>>>(out1, Wih1, bih1, proj);
    {
        const float* p = proj; const float* w = Whh1; const float* bb = bhh1;
        float* o = out1; float* hd = hidden + BATCH * HID; unsigned long long* hb = hbufB;
        void* args[] = {&p, &w, &bb, &o, &hd, &hb};
        hipLaunchCooperativeKernel((const void*)rnn_scan, dim3(256), dim3(512),
                                   args, 0, stream);
    }
}